// Round 1
// baseline (119.625 us; speedup 1.0000x reference)
//
#include <hip/hip_runtime.h>

// ElementalGTOLogNormalSkinCutoff on MI355X (gfx950)
//
// Shapes: B=128, N=128, M=64 neighbours, NG=20, LMAX=2 (A=10 angular comps),
// NSP=4 species + 6 pair combos = 10 m-body groups, FPSIZE = 3*10*20 = 600.
//
// Decomposition: one thread per (atom, g). Each thread accumulates
// T[s][a] for its fixed g over the neighbour list (40 fp32 registers),
// then emits 30 outputs (l, mbody) as quadratic forms of T.
// Key identity: species masks are disjoint, so the combo group
// fp(union) - fp(i) - fp(j) = 2 * lw * sum_a angw[a] * T_i[a] * T_j[a].

#define B_   128
#define N_   128
#define M_   64
#define NG_  20
#define NA_  10
#define NSP_ 4
#define FPSIZE_ 600
#define ATOMS_PER_BLOCK 16
#define BLOCK_THREADS (ATOMS_PER_BLOCK * NG_)   // 320 = 5 waves

__global__ __launch_bounds__(BLOCK_THREADS)
void gto_fp_kernel(const float* __restrict__ coords,   // [B,N,3]
                   const int*   __restrict__ charges,  // [B,N]
                   const int*   __restrict__ counts,   // [B]
                   const int*   __restrict__ neigh,    // [B,N,M]
                   float*       __restrict__ out)      // [B,N,600]
{
    const int tx   = threadIdx.x;
    const int g    = tx % NG_;
    const int la   = tx / NG_;
    const int atom = blockIdx.x * ATOMS_PER_BLOCK + la;
    const int b    = atom / N_;
    const int n    = atom % N_;

    // per-thread (per-g) constants
    const float off         = 0.3f * (float)(g + 1);       // linspace(0,6,21)[1:]
    const float log_off     = __logf(off);
    const float inv_off_spi = 1.0f / (off * 1.7724538509055159f); // 1/(off*sqrt(pi))

    float T[NSP_][NA_];
#pragma unroll
    for (int s = 0; s < NSP_; ++s)
#pragma unroll
        for (int a = 0; a < NA_; ++a) T[s][a] = 0.0f;

    const float cx = coords[atom * 3 + 0];
    const float cy = coords[atom * 3 + 1];
    const float cz = coords[atom * 3 + 2];
    const int   nbase = atom * M_;

    for (int m = 0; m < M_; ++m) {
        const int nb = neigh[nbase + m];
        if (nb < 0) break;                 // valid neighbours are packed first
        const int nidx = b * N_ + nb;
        const float dx = cx - coords[nidx * 3 + 0];
        const float dy = cy - coords[nidx * 3 + 1];
        const float dz = cz - coords[nidx * 3 + 2];
        const int   z  = charges[nidx];

        const float d2     = dx * dx + dy * dy + dz * dz;
        const float inv_d  = __builtin_amdgcn_rsqf(d2);
        const float d      = d2 * inv_d;
        const float inv_d2 = inv_d * inv_d;

        // skin cutoff: dsw = (d - RSWITCH)/(HIGH - RSWITCH)
        const float dsw  = (d - 1.0f) * 0.2f;
        const float dsw2 = dsw * dsw;
        const float dsw3 = dsw2 * dsw;
        const float cut  = 1.0f - dsw3 * fmaf(6.0f, dsw2, fmaf(-15.0f, dsw, 10.0f));

        // log-normal radial basis
        const float sigma2  = __logf(fmaf(2.0f, inv_d2, 1.0f));   // log(1 + W/d^2)
        const float mu      = 0.5f * (__logf(d2) - sigma2);       // log(d) - sigma2/2
        const float inv_s2  = __builtin_amdgcn_rcpf(sigma2);
        const float rsq_s2  = __builtin_amdgcn_rsqf(sigma2);
        const float cen     = log_off - mu;
        const float earg    = -0.5f * inv_s2 * cen * cen;
        const float rad     = inv_off_spi * rsq_s2 * cut * __expf(earg);

        // angular components: (1/d)^(2+l) * x^n y^m z^k
        const float p3 = inv_d2 * inv_d;
        const float p4 = inv_d2 * inv_d2;
        float ang[NA_];
        ang[0] = inv_d2;
        ang[1] = p3 * dx;
        ang[2] = p3 * dy;
        ang[3] = p3 * dz;
        ang[4] = p4 * dx * dx;
        ang[5] = p4 * dx * dy;
        ang[6] = p4 * dy * dy;
        ang[7] = p4 * dx * dz;
        ang[8] = p4 * dy * dz;
        ang[9] = p4 * dz * dz;

        // species routing: z in {1,6,7,8} -> s in {0,1,2,3}
        const float c0 = (z == 1) ? rad : 0.0f;
        const float c1 = (z == 6) ? rad : 0.0f;
        const float c2 = (z == 7) ? rad : 0.0f;
        const float c3 = (z == 8) ? rad : 0.0f;
#pragma unroll
        for (int a = 0; a < NA_; ++a) {
            T[0][a] = fmaf(c0, ang[a], T[0][a]);
            T[1][a] = fmaf(c1, ang[a], T[1][a]);
            T[2][a] = fmaf(c2, ang[a], T[2][a]);
            T[3][a] = fmaf(c3, ang[a], T[3][a]);
        }
    }

    // epilogue: 30 outputs for this g
    const float amask = (n < counts[b]) ? 1.0f : 0.0f;
    float* op = out + atom * FPSIZE_ + g;

    // angw = [1, 1,1,1, 1,2,1,2,2,1]; lw = 1 for all l
#pragma unroll
    for (int l = 0; l < 3; ++l) {
        const int a0 = (l == 0) ? 0 : (l == 1) ? 1 : 4;
        const int a1 = (l == 0) ? 1 : (l == 1) ? 4 : 10;
        // species groups (mbody 0..3)
#pragma unroll
        for (int s = 0; s < NSP_; ++s) {
            float v = 0.0f;
#pragma unroll
            for (int a = a0; a < a1; ++a) {
                const float w = (a == 5 || a == 7 || a == 8) ? 2.0f : 1.0f;
                v = fmaf(w * T[s][a], T[s][a], v);
            }
            op[(l * 10 + s) * NG_] = amask * v;
        }
        // pair combos (mbody 4..9): (0,1),(0,2),(0,3),(1,2),(1,3),(2,3)
        int mb = 4;
#pragma unroll
        for (int i = 0; i < NSP_; ++i) {
#pragma unroll
            for (int j = i + 1; j < NSP_; ++j) {
                float v = 0.0f;
#pragma unroll
                for (int a = a0; a < a1; ++a) {
                    const float w = (a == 5 || a == 7 || a == 8) ? 2.0f : 1.0f;
                    v = fmaf(w * T[i][a], T[j][a], v);
                }
                op[(l * 10 + mb) * NG_] = amask * (2.0f * v);
                ++mb;
            }
        }
    }
}

extern "C" void kernel_launch(void* const* d_in, const int* in_sizes, int n_in,
                              void* d_out, int out_size, void* d_ws, size_t ws_size,
                              hipStream_t stream) {
    const float* coords  = (const float*)d_in[0];
    const int*   charges = (const int*)d_in[1];
    const int*   counts  = (const int*)d_in[2];
    const int*   neigh   = (const int*)d_in[3];
    float*       outp    = (float*)d_out;

    const int atoms  = B_ * N_;                       // 16384
    const int blocks = atoms / ATOMS_PER_BLOCK;       // 1024
    gto_fp_kernel<<<blocks, BLOCK_THREADS, 0, stream>>>(coords, charges, counts, neigh, outp);
}

// Round 2
// 94.122 us; speedup vs baseline: 1.2710x; 1.2710x over previous
//
#include <hip/hip_runtime.h>

// ElementalGTOLogNormalSkinCutoff on MI355X (gfx950) — round 2
//
// Phase 1: per-neighbour shared work computed ONCE (was 20x), neighbours
// bucket-sorted by species into LDS (removes the 4x select-FMA waste).
// Phase 2: thread = (atom, g); 4 branch-free species segment loops,
// ~18 VALU + 24B LDS per neighbour-g.
//
// Folds: 1/d^2 folded into amp (angulars become unit-vector monomials);
// 1/(off*sqrt(pi)) folded into the output scale (outputs are quadratic in T
// -> scale^2); exp() folded to exp2() with -0.5*log2(e)/sigma2 precomputed.

#define B_   128
#define N_   128
#define M_   64
#define NG_  20
#define NSP_ 4
#define FPSIZE_ 600
#define APB  16                     // atoms per block (divides N_, so b uniform)
#define NTASK (APB * M_)            // 1024 neighbour slots per block
#define BLOCK_THREADS (APB * NG_)   // 320 = 5 waves

__global__ __launch_bounds__(BLOCK_THREADS)
void gto_fp_kernel(const float* __restrict__ coords,   // [B,N,3]
                   const int*   __restrict__ charges,  // [B,N]
                   const int*   __restrict__ counts,   // [B]
                   const int*   __restrict__ neigh,    // [B,N,M]
                   float*       __restrict__ out)      // [B,N,600]
{
    __shared__ float4 sA[APB][M_];          // ux, uy, uz, mu
    __shared__ float2 sB[APB][M_];          // fold = -0.5*log2e/sigma2, amp
    __shared__ int s_cnt[APB][NSP_];
    __shared__ int s_start[APB][NSP_];
    __shared__ int s_pos[APB][NSP_];

    const int tid = threadIdx.x;
    const int blockBase = blockIdx.x * APB;
    const int bidx = blockBase / N_;        // uniform: APB divides N_

    if (tid < APB * NSP_) ((int*)s_cnt)[tid] = 0;
    __syncthreads();

    // ---------------- phase 1: build + count ----------------
    float4 rA[4]; float2 rB[4]; int rls[4]; int nrec = 0;
    for (int t = tid; t < NTASK; t += BLOCK_THREADS) {
        const int la = t >> 6;
        const int m  = t & 63;
        const int atom = blockBase + la;
        const int nb = neigh[atom * M_ + m];
        if (nb < 0) continue;
        const int nidx = bidx * N_ + nb;
        const float dx = coords[atom * 3 + 0] - coords[nidx * 3 + 0];
        const float dy = coords[atom * 3 + 1] - coords[nidx * 3 + 1];
        const float dz = coords[atom * 3 + 2] - coords[nidx * 3 + 2];
        const int   z  = charges[nidx];

        const float d2     = dx * dx + dy * dy + dz * dz;
        const float inv_d  = __builtin_amdgcn_rsqf(d2);
        const float d      = d2 * inv_d;
        const float inv_d2 = inv_d * inv_d;
        const float ux = dx * inv_d, uy = dy * inv_d, uz = dz * inv_d;

        // skin cutoff
        const float dsw  = (d - 1.0f) * 0.2f;
        const float dsw2 = dsw * dsw;
        const float cut  = 1.0f - dsw2 * dsw * fmaf(6.0f, dsw2, fmaf(-15.0f, dsw, 10.0f));

        // log-normal parameters
        const float sigma2 = __logf(fmaf(2.0f, inv_d2, 1.0f));     // log(1 + W/d^2)
        const float mu     = 0.5f * (__logf(d2) - sigma2);         // log(d) - sigma2/2
        const float fold   = -0.72134752f * __builtin_amdgcn_rcpf(sigma2); // -0.5*log2e/s2
        const float amp    = __builtin_amdgcn_rsqf(sigma2) * cut * inv_d2;

        const int s = (z == 1) ? 0 : (z - 5);   // {1,6,7,8} -> {0,1,2,3}
        atomicAdd(&s_cnt[la][s], 1);
        rA[nrec] = make_float4(ux, uy, uz, mu);
        rB[nrec] = make_float2(fold, amp);
        rls[nrec] = (la << 2) | s;
        ++nrec;
    }
    __syncthreads();

    if (tid < APB) {
        const int c0 = s_cnt[tid][0], c1 = s_cnt[tid][1], c2 = s_cnt[tid][2];
        s_start[tid][0] = 0;            s_pos[tid][0] = 0;
        s_start[tid][1] = c0;           s_pos[tid][1] = c0;
        s_start[tid][2] = c0 + c1;      s_pos[tid][2] = c0 + c1;
        s_start[tid][3] = c0 + c1 + c2; s_pos[tid][3] = c0 + c1 + c2;
    }
    __syncthreads();

    for (int r = 0; r < nrec; ++r) {
        const int la = rls[r] >> 2, s = rls[r] & 3;
        const int slot = atomicAdd(&s_pos[la][s], 1);
        sA[la][slot] = rA[r];
        sB[la][slot] = rB[r];
    }
    __syncthreads();

    // ---------------- phase 2: accumulate T, emit outputs ----------------
    const int g  = tid % NG_;
    const int la = tid / NG_;
    const int atom = blockBase + la;
    const int n = atom % N_;

    const float off         = 0.3f * (float)(g + 1);
    const float log_off     = __logf(off);
    const float inv_off_spi = 1.0f / (off * 1.7724538509055159f);

    float T[NSP_][10];
#pragma unroll
    for (int s = 0; s < NSP_; ++s)
#pragma unroll
        for (int a = 0; a < 10; ++a) T[s][a] = 0.0f;

#define ACC(SS)                                                               \
    {                                                                         \
        const int e0 = s_start[la][SS];                                       \
        const int e1 = e0 + s_cnt[la][SS];                                    \
        for (int m = e0; m < e1; ++m) {                                       \
            const float4 A  = sA[la][m];                                      \
            const float2 Bv = sB[la][m];                                      \
            const float cen = log_off - A.w;                                  \
            const float ex  = __builtin_amdgcn_exp2f(Bv.x * cen * cen);       \
            const float rad = Bv.y * ex;                                      \
            const float rx = rad * A.x, ry = rad * A.y, rz = rad * A.z;       \
            T[SS][0] += rad;                                                  \
            T[SS][1] += rx;  T[SS][2] += ry;  T[SS][3] += rz;                 \
            T[SS][4] = fmaf(rx, A.x, T[SS][4]);                               \
            T[SS][5] = fmaf(rx, A.y, T[SS][5]);                               \
            T[SS][6] = fmaf(ry, A.y, T[SS][6]);                               \
            T[SS][7] = fmaf(rx, A.z, T[SS][7]);                               \
            T[SS][8] = fmaf(ry, A.z, T[SS][8]);                               \
            T[SS][9] = fmaf(rz, A.z, T[SS][9]);                               \
        }                                                                     \
    }
    ACC(0) ACC(1) ACC(2) ACC(3)
#undef ACC

    // output scale: atom mask * (1/(off*sqrt(pi)))^2  (quadratic in T)
    const float amask = (n < counts[bidx]) ? 1.0f : 0.0f;
    const float scale = amask * inv_off_spi * inv_off_spi;
    float* op = out + atom * FPSIZE_ + g;

    // angw = [1, 1,1,1, 1,2,1,2,2,1]; lw = 1 for all l
#pragma unroll
    for (int l = 0; l < 3; ++l) {
        const int a0 = (l == 0) ? 0 : (l == 1) ? 1 : 4;
        const int a1 = (l == 0) ? 1 : (l == 1) ? 4 : 10;
#pragma unroll
        for (int s = 0; s < NSP_; ++s) {
            float v = 0.0f;
#pragma unroll
            for (int a = a0; a < a1; ++a) {
                const float w = (a == 5 || a == 7 || a == 8) ? 2.0f : 1.0f;
                v = fmaf(w * T[s][a], T[s][a], v);
            }
            op[(l * 10 + s) * NG_] = scale * v;
        }
        int mb = 4;
#pragma unroll
        for (int i = 0; i < NSP_; ++i) {
#pragma unroll
            for (int j = i + 1; j < NSP_; ++j) {
                float v = 0.0f;
#pragma unroll
                for (int a = a0; a < a1; ++a) {
                    const float w = (a == 5 || a == 7 || a == 8) ? 2.0f : 1.0f;
                    v = fmaf(w * T[i][a], T[j][a], v);
                }
                op[(l * 10 + mb) * NG_] = scale * (2.0f * v);
                ++mb;
            }
        }
    }
}

extern "C" void kernel_launch(void* const* d_in, const int* in_sizes, int n_in,
                              void* d_out, int out_size, void* d_ws, size_t ws_size,
                              hipStream_t stream) {
    const float* coords  = (const float*)d_in[0];
    const int*   charges = (const int*)d_in[1];
    const int*   counts  = (const int*)d_in[2];
    const int*   neigh   = (const int*)d_in[3];
    float*       outp    = (float*)d_out;

    const int blocks = (B_ * N_) / APB;   // 1024
    gto_fp_kernel<<<blocks, BLOCK_THREADS, 0, stream>>>(coords, charges, counts, neigh, outp);
}

// Round 3
// 86.541 us; speedup vs baseline: 1.3823x; 1.0876x over previous
//
#include <hip/hip_runtime.h>

// ElementalGTOLogNormalSkinCutoff on MI355X (gfx950) — round 3
//
// Two-phase: phase 1 computes per-neighbour shared quantities once and
// bucket-sorts neighbours by species into LDS; phase 2 (thread = atom,g)
// runs 4 branch-free species-segment loops with static T[s][a] indexing.
//
// Round-3 fixes vs round 2:
//  * Phase 1 fully unrolled to 4 statically-indexed iterations — round 2's
//    dynamically-indexed record arrays spilled to scratch (VALUBusy 0.6%!).
//  * LDS rows padded to M+1 — the 1024-float row stride aliased all atoms
//    onto the same banks (451k SQ_LDS_BANK_CONFLICT).

#define B_   128
#define N_   128
#define M_   64
#define NG_  20
#define NSP_ 4
#define FPSIZE_ 600
#define APB  16                     // atoms per block (divides N_, so b uniform)
#define NTASK (APB * M_)            // 1024 neighbour slots per block
#define BLOCK_THREADS (APB * NG_)   // 320 = 5 waves
#define P1ITER 4                    // ceil(1024/320)

__global__ __launch_bounds__(BLOCK_THREADS)
void gto_fp_kernel(const float* __restrict__ coords,   // [B,N,3]
                   const int*   __restrict__ charges,  // [B,N]
                   const int*   __restrict__ counts,   // [B]
                   const int*   __restrict__ neigh,    // [B,N,M]
                   float*       __restrict__ out)      // [B,N,600]
{
    __shared__ float4 sA[APB][M_ + 1];      // ux, uy, uz, mu   (padded row)
    __shared__ float2 sB[APB][M_ + 1];      // fold, amp        (padded row)
    __shared__ int s_cnt[APB][NSP_];
    __shared__ int s_start[APB][NSP_];
    __shared__ int s_pos[APB][NSP_];

    const int tid = threadIdx.x;
    const int blockBase = blockIdx.x * APB;
    const int bidx = blockBase / N_;        // uniform: APB divides N_

    if (tid < APB * NSP_) ((int*)s_cnt)[tid] = 0;
    __syncthreads();

    // ---------------- phase 1: build records + count (all static regs) ----
    float4 rA[P1ITER];
    float2 rB[P1ITER];
    int    rls[P1ITER];
    bool   rv[P1ITER];

#pragma unroll
    for (int it = 0; it < P1ITER; ++it) {
        const int t = tid + it * BLOCK_THREADS;
        bool v = (t < NTASK);
        int la = 0, s = 0;
        float4 A = make_float4(0.f, 0.f, 0.f, 0.f);
        float2 Bv = make_float2(0.f, 0.f);
        if (v) {
            la = t >> 6;
            const int m  = t & 63;
            const int atom = blockBase + la;
            const int nb = neigh[atom * M_ + m];
            if (nb < 0) {
                v = false;
            } else {
                const int nidx = bidx * N_ + nb;
                const float dx = coords[atom * 3 + 0] - coords[nidx * 3 + 0];
                const float dy = coords[atom * 3 + 1] - coords[nidx * 3 + 1];
                const float dz = coords[atom * 3 + 2] - coords[nidx * 3 + 2];
                const int   z  = charges[nidx];

                const float d2     = dx * dx + dy * dy + dz * dz;
                const float inv_d  = __builtin_amdgcn_rsqf(d2);
                const float d      = d2 * inv_d;
                const float inv_d2 = inv_d * inv_d;

                const float dsw  = (d - 1.0f) * 0.2f;
                const float dsw2 = dsw * dsw;
                const float cut  = 1.0f - dsw2 * dsw * fmaf(6.0f, dsw2, fmaf(-15.0f, dsw, 10.0f));

                const float sigma2 = __logf(fmaf(2.0f, inv_d2, 1.0f));
                const float mu     = 0.5f * (__logf(d2) - sigma2);
                const float fold   = -0.72134752f * __builtin_amdgcn_rcpf(sigma2); // -0.5*log2e/s2
                const float amp    = __builtin_amdgcn_rsqf(sigma2) * cut * inv_d2;

                s = (z == 1) ? 0 : (z - 5);   // {1,6,7,8} -> {0,1,2,3}
                A  = make_float4(dx * inv_d, dy * inv_d, dz * inv_d, mu);
                Bv = make_float2(fold, amp);
                atomicAdd(&s_cnt[la][s], 1);
            }
        }
        rA[it] = A; rB[it] = Bv; rls[it] = (la << 2) | s; rv[it] = v;
    }
    __syncthreads();

    if (tid < APB) {
        const int c0 = s_cnt[tid][0], c1 = s_cnt[tid][1], c2 = s_cnt[tid][2];
        s_start[tid][0] = 0;            s_pos[tid][0] = 0;
        s_start[tid][1] = c0;           s_pos[tid][1] = c0;
        s_start[tid][2] = c0 + c1;      s_pos[tid][2] = c0 + c1;
        s_start[tid][3] = c0 + c1 + c2; s_pos[tid][3] = c0 + c1 + c2;
    }
    __syncthreads();

#pragma unroll
    for (int it = 0; it < P1ITER; ++it) {
        if (rv[it]) {
            const int la = rls[it] >> 2, s = rls[it] & 3;
            const int slot = atomicAdd(&s_pos[la][s], 1);
            sA[la][slot] = rA[it];
            sB[la][slot] = rB[it];
        }
    }
    __syncthreads();

    // ---------------- phase 2: accumulate T, emit outputs ----------------
    const int g  = tid % NG_;
    const int la = tid / NG_;
    const int atom = blockBase + la;
    const int n = atom % N_;

    const float off         = 0.3f * (float)(g + 1);
    const float log_off     = __logf(off);
    const float inv_off_spi = 1.0f / (off * 1.7724538509055159f);

    float T[NSP_][10];
#pragma unroll
    for (int s = 0; s < NSP_; ++s)
#pragma unroll
        for (int a = 0; a < 10; ++a) T[s][a] = 0.0f;

#define ACC(SS)                                                               \
    {                                                                         \
        const int e0 = s_start[la][SS];                                       \
        const int e1 = e0 + s_cnt[la][SS];                                    \
        for (int m = e0; m < e1; ++m) {                                       \
            const float4 A  = sA[la][m];                                      \
            const float2 Bv = sB[la][m];                                      \
            const float cen = log_off - A.w;                                  \
            const float ex  = __builtin_amdgcn_exp2f(Bv.x * cen * cen);       \
            const float rad = Bv.y * ex;                                      \
            const float rx = rad * A.x, ry = rad * A.y, rz = rad * A.z;       \
            T[SS][0] += rad;                                                  \
            T[SS][1] += rx;  T[SS][2] += ry;  T[SS][3] += rz;                 \
            T[SS][4] = fmaf(rx, A.x, T[SS][4]);                               \
            T[SS][5] = fmaf(rx, A.y, T[SS][5]);                               \
            T[SS][6] = fmaf(ry, A.y, T[SS][6]);                               \
            T[SS][7] = fmaf(rx, A.z, T[SS][7]);                               \
            T[SS][8] = fmaf(ry, A.z, T[SS][8]);                               \
            T[SS][9] = fmaf(rz, A.z, T[SS][9]);                               \
        }                                                                     \
    }
    ACC(0) ACC(1) ACC(2) ACC(3)
#undef ACC

    // output scale: atom mask * (1/(off*sqrt(pi)))^2  (quadratic in T)
    const float amask = (n < counts[bidx]) ? 1.0f : 0.0f;
    const float scale = amask * inv_off_spi * inv_off_spi;
    float* op = out + atom * FPSIZE_ + g;

    // angw = [1, 1,1,1, 1,2,1,2,2,1]; lw = 1 for all l
#pragma unroll
    for (int l = 0; l < 3; ++l) {
        const int a0 = (l == 0) ? 0 : (l == 1) ? 1 : 4;
        const int a1 = (l == 0) ? 1 : (l == 1) ? 4 : 10;
#pragma unroll
        for (int s = 0; s < NSP_; ++s) {
            float v = 0.0f;
#pragma unroll
            for (int a = a0; a < a1; ++a) {
                const float w = (a == 5 || a == 7 || a == 8) ? 2.0f : 1.0f;
                v = fmaf(w * T[s][a], T[s][a], v);
            }
            op[(l * 10 + s) * NG_] = scale * v;
        }
        int mb = 4;
#pragma unroll
        for (int i = 0; i < NSP_; ++i) {
#pragma unroll
            for (int j = i + 1; j < NSP_; ++j) {
                float v = 0.0f;
#pragma unroll
                for (int a = a0; a < a1; ++a) {
                    const float w = (a == 5 || a == 7 || a == 8) ? 2.0f : 1.0f;
                    v = fmaf(w * T[i][a], T[j][a], v);
                }
                op[(l * 10 + mb) * NG_] = scale * (2.0f * v);
                ++mb;
            }
        }
    }
}

extern "C" void kernel_launch(void* const* d_in, const int* in_sizes, int n_in,
                              void* d_out, int out_size, void* d_ws, size_t ws_size,
                              hipStream_t stream) {
    const float* coords  = (const float*)d_in[0];
    const int*   charges = (const int*)d_in[1];
    const int*   counts  = (const int*)d_in[2];
    const int*   neigh   = (const int*)d_in[3];
    float*       outp    = (float*)d_out;

    const int blocks = (B_ * N_) / APB;   // 1024
    gto_fp_kernel<<<blocks, BLOCK_THREADS, 0, stream>>>(coords, charges, counts, neigh, outp);
}

// Round 5
// 84.085 us; speedup vs baseline: 1.4227x; 1.0292x over previous
//
#include <hip/hip_runtime.h>

// ElementalGTOLogNormalSkinCutoff on MI355X (gfx950) — round 5
//
// Two-phase: phase 1 computes per-neighbour shared quantities once and
// bucket-sorts neighbours by species into LDS; phase 2 (thread = atom,g)
// runs 4 branch-free species-segment loops with static T[s][a] indexing.
//
// Round-5 fix vs round 4 (NaN): boundary neighbours with dist ~= 6.0 can
// recompute on-GPU to d >= 6 (rsqrt ~2ulp), making cut (and thus amp)
// tiny-NEGATIVE -> log2(amp) = NaN. Clamp amp to 1e-30 before the log:
// contribution becomes ~0 instead of ~-1e-7 — far below the abs threshold.

#define B_   128
#define N_   128
#define M_   64
#define NG_  20
#define NSP_ 4
#define FPSIZE_ 600
#define APB  16                     // atoms per block (divides N_, so b uniform)
#define NTASK (APB * M_)            // 1024 neighbour slots per block
#define BLOCK_THREADS (APB * NG_)   // 320 = 5 waves
#define P1ITER 4                    // ceil(1024/320)

__global__ __launch_bounds__(BLOCK_THREADS)
void gto_fp_kernel(const float* __restrict__ coords,   // [B,N,3]
                   const int*   __restrict__ charges,  // [B,N]
                   const int*   __restrict__ counts,   // [B]
                   const int*   __restrict__ neigh,    // [B,N,M]
                   float*       __restrict__ out)      // [B,N,600]
{
    __shared__ float4 sP[APB][M_ + 1];      // c0, c1, c2, ux  (padded row)
    __shared__ float2 sQ[APB][M_ + 1];      // uy, uz          (padded row)
    __shared__ int s_cnt[APB][NSP_];
    __shared__ int s_start[APB][NSP_];
    __shared__ int s_pos[APB][NSP_];

    const int tid = threadIdx.x;
    const int blockBase = blockIdx.x * APB;
    const int bidx = blockBase / N_;        // uniform: APB divides N_

    if (tid < APB * NSP_) ((int*)s_cnt)[tid] = 0;
    __syncthreads();

    // ---------------- phase 1: build records + count (all static regs) ----
    float4 rP[P1ITER];
    float2 rQ[P1ITER];
    int    rls[P1ITER];
    bool   rv[P1ITER];

#pragma unroll
    for (int it = 0; it < P1ITER; ++it) {
        const int t = tid + it * BLOCK_THREADS;
        bool v = (t < NTASK);
        int la = 0, s = 0;
        float4 P = make_float4(0.f, 0.f, 0.f, 0.f);
        float2 Q = make_float2(0.f, 0.f);
        if (v) {
            la = t >> 6;
            const int m  = t & 63;
            const int atom = blockBase + la;
            const int nb = neigh[atom * M_ + m];
            if (nb < 0) {
                v = false;
            } else {
                const int nidx = bidx * N_ + nb;
                const float dx = coords[atom * 3 + 0] - coords[nidx * 3 + 0];
                const float dy = coords[atom * 3 + 1] - coords[nidx * 3 + 1];
                const float dz = coords[atom * 3 + 2] - coords[nidx * 3 + 2];
                const int   z  = charges[nidx];

                const float d2     = dx * dx + dy * dy + dz * dz;
                const float inv_d  = __builtin_amdgcn_rsqf(d2);
                const float d      = d2 * inv_d;
                const float inv_d2 = inv_d * inv_d;

                const float dsw  = (d - 1.0f) * 0.2f;
                const float dsw2 = dsw * dsw;
                const float cut  = 1.0f - dsw2 * dsw * fmaf(6.0f, dsw2, fmaf(-15.0f, dsw, 10.0f));

                const float sigma2 = __logf(fmaf(2.0f, inv_d2, 1.0f));     // log(1+W/d^2)
                const float mu     = 0.5f * (__logf(d2) - sigma2);         // log(d)-s2/2
                const float amp    = fmaxf(__builtin_amdgcn_rsqf(sigma2) * cut * inv_d2,
                                           1.0e-30f);   // clamp: cut can be ~-1e-7 at d~6

                const float F  = -0.72134752f * __builtin_amdgcn_rcpf(sigma2); // -0.5*log2e/s2
                const float Fm = F * mu;
                const float c0 = F;
                const float c1 = -(Fm + Fm);
                const float c2 = fmaf(Fm, mu, __log2f(amp));

                s = (z == 1) ? 0 : (z - 5);   // {1,6,7,8} -> {0,1,2,3}
                P = make_float4(c0, c1, c2, dx * inv_d);
                Q = make_float2(dy * inv_d, dz * inv_d);
                atomicAdd(&s_cnt[la][s], 1);
            }
        }
        rP[it] = P; rQ[it] = Q; rls[it] = (la << 2) | s; rv[it] = v;
    }
    __syncthreads();

    if (tid < APB) {
        const int c0 = s_cnt[tid][0], c1 = s_cnt[tid][1], c2 = s_cnt[tid][2];
        s_start[tid][0] = 0;            s_pos[tid][0] = 0;
        s_start[tid][1] = c0;           s_pos[tid][1] = c0;
        s_start[tid][2] = c0 + c1;      s_pos[tid][2] = c0 + c1;
        s_start[tid][3] = c0 + c1 + c2; s_pos[tid][3] = c0 + c1 + c2;
    }
    __syncthreads();

#pragma unroll
    for (int it = 0; it < P1ITER; ++it) {
        if (rv[it]) {
            const int la = rls[it] >> 2, s = rls[it] & 3;
            const int slot = atomicAdd(&s_pos[la][s], 1);
            sP[la][slot] = rP[it];
            sQ[la][slot] = rQ[it];
        }
    }
    __syncthreads();

    // ---------------- phase 2: accumulate T, emit outputs ----------------
    const int g  = tid % NG_;
    const int la = tid / NG_;
    const int atom = blockBase + la;
    const int n = atom % N_;

    const float off         = 0.3f * (float)(g + 1);
    const float lo          = __logf(off);            // natural-log space
    const float lo2         = lo * lo;
    const float inv_off_spi = 1.0f / (off * 1.7724538509055159f);

    float T[NSP_][10];
#pragma unroll
    for (int s = 0; s < NSP_; ++s)
#pragma unroll
        for (int a = 0; a < 10; ++a) T[s][a] = 0.0f;

#define BODY(SS, P, Q)                                                        \
    {                                                                         \
        const float rad = __builtin_amdgcn_exp2f(                             \
            fmaf(P.x, lo2, fmaf(P.y, lo, P.z)));                              \
        const float rx = rad * P.w, ry = rad * Q.x, rz = rad * Q.y;           \
        T[SS][0] += rad;                                                      \
        T[SS][1] += rx;  T[SS][2] += ry;  T[SS][3] += rz;                     \
        T[SS][4] = fmaf(rx, P.w, T[SS][4]);                                   \
        T[SS][5] = fmaf(rx, Q.x, T[SS][5]);                                   \
        T[SS][6] = fmaf(ry, Q.x, T[SS][6]);                                   \
        T[SS][7] = fmaf(rx, Q.y, T[SS][7]);                                   \
        T[SS][8] = fmaf(ry, Q.y, T[SS][8]);                                   \
        T[SS][9] = fmaf(rz, Q.y, T[SS][9]);                                   \
    }

#define ACC(SS)                                                               \
    {                                                                         \
        const int e0 = s_start[la][SS];                                       \
        const int e1 = e0 + s_cnt[la][SS];                                    \
        int m = e0;                                                           \
        for (; m + 1 < e1; m += 2) {                                          \
            const float4 Pa = sP[la][m];     const float2 Qa = sQ[la][m];     \
            const float4 Pb = sP[la][m + 1]; const float2 Qb = sQ[la][m + 1]; \
            BODY(SS, Pa, Qa)                                                  \
            BODY(SS, Pb, Qb)                                                  \
        }                                                                     \
        if (m < e1) {                                                         \
            const float4 Pa = sP[la][m]; const float2 Qa = sQ[la][m];         \
            BODY(SS, Pa, Qa)                                                  \
        }                                                                     \
    }
    ACC(0) ACC(1) ACC(2) ACC(3)
#undef ACC
#undef BODY

    // output scale: atom mask * (1/(off*sqrt(pi)))^2  (quadratic in T)
    const float amask = (n < counts[bidx]) ? 1.0f : 0.0f;
    const float scale = amask * inv_off_spi * inv_off_spi;
    float* op = out + atom * FPSIZE_ + g;

    // angw = [1, 1,1,1, 1,2,1,2,2,1]; lw = 1 for all l
#pragma unroll
    for (int l = 0; l < 3; ++l) {
        const int a0 = (l == 0) ? 0 : (l == 1) ? 1 : 4;
        const int a1 = (l == 0) ? 1 : (l == 1) ? 4 : 10;
#pragma unroll
        for (int s = 0; s < NSP_; ++s) {
            float v = 0.0f;
#pragma unroll
            for (int a = a0; a < a1; ++a) {
                const float w = (a == 5 || a == 7 || a == 8) ? 2.0f : 1.0f;
                v = fmaf(w * T[s][a], T[s][a], v);
            }
            op[(l * 10 + s) * NG_] = scale * v;
        }
        int mb = 4;
#pragma unroll
        for (int i = 0; i < NSP_; ++i) {
#pragma unroll
            for (int j = i + 1; j < NSP_; ++j) {
                float v = 0.0f;
#pragma unroll
                for (int a = a0; a < a1; ++a) {
                    const float w = (a == 5 || a == 7 || a == 8) ? 2.0f : 1.0f;
                    v = fmaf(w * T[i][a], T[j][a], v);
                }
                op[(l * 10 + mb) * NG_] = scale * (2.0f * v);
                ++mb;
            }
        }
    }
}

extern "C" void kernel_launch(void* const* d_in, const int* in_sizes, int n_in,
                              void* d_out, int out_size, void* d_ws, size_t ws_size,
                              hipStream_t stream) {
    const float* coords  = (const float*)d_in[0];
    const int*   charges = (const int*)d_in[1];
    const int*   counts  = (const int*)d_in[2];
    const int*   neigh   = (const int*)d_in[3];
    float*       outp    = (float*)d_out;

    const int blocks = (B_ * N_) / APB;   // 1024
    gto_fp_kernel<<<blocks, BLOCK_THREADS, 0, stream>>>(coords, charges, counts, neigh, outp);
}